// Round 14
// baseline (248.283 us; speedup 1.0000x reference)
//
#include <hip/hip_runtime.h>
#include <math.h>

namespace {

constexpr int C_ = 3, T_ = 3000, F_ = 103, NB_ = 6;
constexpr int TT = 20;                       // t-steps per tile
constexpr int NT = 3;                        // tiles per block; 3000/(20*3)=50 chunks
constexpr int BS[NB_]  = {1, 10, 20, 30, 40, 61};
constexpr int BNB[NB_] = {10, 11, 11, 11, 22, 16};
// packed-on-global-parity weight/spec word geometry
constexpr int WSTART[NB_] = {0, 5, 10, 15, 20, 30};  // BS[i]>>1
constexpr int WCNT[NB_]   = {6, 6, 6, 6, 11, 9};     // words covering each band
constexpr int WOFF[NB_]   = {0, 6, 12, 18, 24, 35};  // cumsum WCNT; row = 44
constexpr int WROW = 44;
constexpr int WTOTU = 18 * WROW;             // 792 packed u32 weights
constexpr int SPW = 39;                      // packed spec words per (c,tt) row (f 0..77)
constexpr int SPECW = C_ * TT * SPW;         // 2340
constexpr int ERS = 52;                      // enh row stride (u32), f 0..103
constexpr int EPL = TT * ERS;                // 1040 per c plane
constexpr int POOLU = 3 * EPL;               // 3120 u32 >= SPECW (aliased)
constexpr int PLANE = T_ * F_;               // 309000

__device__ __forceinline__ float softplus_(float x) {
  return fmaxf(x, 0.0f) + log1pf(expf(-fabsf(x)));
}
__device__ __forceinline__ float sigmoid_(float z) {
  return 1.0f / (1.0f + __expf(-z));
}
__device__ __forceinline__ float gelu_(float x) {
  return x * sigmoid_(1.595769122f * x * (1.0f + 0.044715f * x * x));
}
__device__ __forceinline__ unsigned bf16_rne_(float x) {
  unsigned b = __float_as_uint(x);
  b += 0x7FFFu + ((b >> 16) & 1u);
  return b >> 16;
}
__device__ __forceinline__ float bl_(unsigned u) { return __uint_as_float(u << 16); }
__device__ __forceinline__ float bh_(unsigned u) { return __uint_as_float(u & 0xffff0000u); }

// ---- pre-kernel: global-parity packed bf16 gaussian bank + folded proj/BN -----
__global__ __launch_bounds__(128)
void prep_kernel(const float* __restrict__ centers,
                 const float* __restrict__ widths,
                 const float* __restrict__ gains,
                 const float* __restrict__ proj_w,
                 const float* __restrict__ proj_b,
                 const float* __restrict__ bn_gamma,
                 const float* __restrict__ bn_beta,
                 const float* __restrict__ bn_mean,
                 const float* __restrict__ bn_var,
                 float* __restrict__ ws)
{
  unsigned* wsU = (unsigned*)ws;
  const int q = threadIdx.x;
  if (q < 108) {
    int i = q / 18;
    int p = q - i * 18;                       // c*6+n
    int s = BS[i], nb = BNB[i];
    float mu = softplus_(centers[q]) + (float)s;
    mu = fminf(fmaxf(mu, (float)s), (float)(s + nb - 1));
    float sd = softplus_(widths[q]) + 0.001f;
    sd = fminf(fmaxf(sd, 0.5f), 2.0f * (float)nb / 6.0f);
    float sum = 0.0f;
    for (int f = 0; f < nb; ++f) {
      float d = ((float)f - mu) / sd;
      sum += __expf(-0.5f * d * d);
    }
    float sc = gains[q] / (sum + 1e-6f);
    float wtmp[22];
    for (int f = 0; f < nb; ++f) {
      float d = ((float)f - mu) / sd;
      wtmp[f] = sc * __expf(-0.5f * d * d);
    }
    for (int e = 0; e < WCNT[i]; ++e) {
      int flo = 2 * (WSTART[i] + e) - s;      // band-local index of lo slot
      int fhi = flo + 1;
      unsigned lo = (flo >= 0 && flo < nb) ? bf16_rne_(wtmp[flo]) : 0u;
      unsigned hi = (fhi >= 0 && fhi < nb) ? bf16_rne_(wtmp[fhi]) : 0u;
      wsU[p * WROW + WOFF[i] + e] = lo | (hi << 16);
    }
  } else if (q < 117) {
    int k = q - 108, d = k / 3;
    float sc = bn_gamma[d] / sqrtf(bn_var[d] + 1e-5f);
    ws[WTOTU + k] = proj_w[k] * sc;
  } else if (q < 120) {
    int d = q - 117;
    float sc = bn_gamma[d] / sqrtf(bn_var[d] + 1e-5f);
    ws[WTOTU + 9 + d] = (proj_b[d] - bn_mean[d]) * sc + bn_beta[d];
  }
}

// ---- main kernel: R13 structure + packed-bf16 sBand -> 7 blocks/CU ------------
__global__ __launch_bounds__(256, 7)
void sleepband_kernel(const float* __restrict__ spec,
                      const float* __restrict__ ws,
                      const float* __restrict__ align_w,
                      const float* __restrict__ align_b,
                      const float* __restrict__ fc1_w,
                      const float* __restrict__ fc1_b,
                      const float* __restrict__ fc2_w,
                      const float* __restrict__ fc2_b,
                      const float* __restrict__ band_gain,
                      const float* __restrict__ gate_w,
                      const float* __restrict__ gate_b,
                      float* __restrict__ out)
{
  // pool (u32): [stage/A] packed spec [c][tt][39]  ||  [B2/final] packed enh [c][tt][52]
  __shared__ unsigned sPoolU[POOLU];
  __shared__ unsigned sWu[WTOTU];                       // packed bf16 weight pairs
  __shared__ __align__(4) unsigned short sBand16[TT][110];  // bf16; dword stride 55 (odd)
  __shared__ float sAw[54], sAb[18], sF1[108], sF1b[6], sF2[108], sF2b[18],
                   sBg[6], sGw[9], sGb[3], sPw[9], sPb[3];

  const int tid = threadIdx.x;
  const int b   = blockIdx.y;
  const float* specB = spec + (size_t)b * C_ * PLANE;
  float* outBase = out + (size_t)b * C_ * PLANE;
  const unsigned* wsU = (const unsigned*)ws;

  // ---- one-time prologue: params + packed gaussian weights ----
  for (int k = tid; k < WTOTU; k += 256) sWu[k] = wsU[k];
  if (tid < 54)  sAw[tid]  = align_w[tid];
  if (tid < 18)  sAb[tid]  = align_b[tid];
  if (tid < 108) sF1[tid]  = fc1_w[tid];
  if (tid < 6)   sF1b[tid] = fc1_b[tid];
  if (tid < 108) sF2[tid]  = fc2_w[tid];
  if (tid < 18)  sF2b[tid] = fc2_b[tid];
  if (tid < 6)   sBg[tid]  = band_gain[tid];
  if (tid < 9)   sGw[tid]  = gate_w[tid];
  if (tid < 3)   sGb[tid]  = gate_b[tid];
  if (tid < 9)   sPw[tid]  = ws[WTOTU + tid];
  if (tid < 3)   sPb[tid]  = ws[WTOTU + 9 + tid];

  for (int tile = 0; tile < NT; ++tile) {
    const int t0 = (blockIdx.x * NT + tile) * TT;

    // ---- stage spec as packed bf16 pairs (f 0..77), float2 loads + trunc ----
    for (int li = tid; li < SPECW; li += 256) {
      int c   = li / (TT * SPW);
      int rem = li - c * (TT * SPW);
      int tt  = rem / SPW;
      int w   = rem - tt * SPW;
      const float2 pr = *(const float2*)(specB + (size_t)c * PLANE +
                                         (size_t)(t0 + tt) * F_ + 2 * w);
      sPoolU[li] = (__float_as_uint(pr.x) >> 16) |
                   (__float_as_uint(pr.y) & 0xffff0000u);
    }
    __syncthreads();

    // ---- Phase A: filt via packed spec x packed weights, n-pair tasks (180) ----
    if (tid < 180) {
      const int g  = tid / TT;             // c*3 + np
      const int tt = tid - g * TT;
      const int c  = g / 3;
      const int np = g - c * 3;
      const int n0 = 2 * np;
      const unsigned* srow = &sPoolU[(c * TT + tt) * SPW];
      const unsigned* w0 = &sWu[(c * 6 + n0) * WROW];
      const unsigned* w1 = w0 + WROW;
      #pragma unroll
      for (int i = 0; i < NB_; ++i) {
        float a0 = 0.0f, a1 = 0.0f;
        #pragma unroll
        for (int e = 0; e < WCNT[i]; ++e) {
          unsigned su = srow[WSTART[i] + e];
          float s0 = bl_(su), s1 = bh_(su);
          unsigned u0 = w0[WOFF[i] + e], u1 = w1[WOFF[i] + e];
          a0 += s0 * bl_(u0); a0 += s1 * bh_(u0);
          a1 += s0 * bl_(u1); a1 += s1 * bh_(u1);
        }
        // pack two bf16 (truncate) into the aligned u32 pair slot
        const int col = (i * 3 + c) * 6 + n0;          // even
        *(unsigned*)&sBand16[tt][col] =
            (__float_as_uint(a0) >> 16) | (__float_as_uint(a1) & 0xffff0000u);
      }
    }
    __syncthreads();

    // ---- Phase B: align + MLP + softmax + scale (120 tasks) ----
    if (tid < 6 * TT) {
      int n  = tid / TT;
      int tt = tid - n * TT;
      float al[18];
      #pragma unroll
      for (int i = 0; i < 6; ++i) {
        float f0 = __uint_as_float((unsigned)sBand16[tt][(i * 3 + 0) * 6 + n] << 16);
        float f1 = __uint_as_float((unsigned)sBand16[tt][(i * 3 + 1) * 6 + n] << 16);
        float f2 = __uint_as_float((unsigned)sBand16[tt][(i * 3 + 2) * 6 + n] << 16);
        #pragma unroll
        for (int d = 0; d < 3; ++d)
          al[i * 3 + d] = sAw[i * 9 + d * 3 + 0] * f0 + sAw[i * 9 + d * 3 + 1] * f1 +
                          sAw[i * 9 + d * 3 + 2] * f2 + sAb[i * 3 + d];
      }
      float h[6];
      #pragma unroll
      for (int o = 0; o < 6; ++o) {
        float acc = sF1b[o];
        #pragma unroll
        for (int k = 0; k < 18; ++k) acc += sF1[o * 18 + k] * al[k];
        h[o] = gelu_(acc);
      }
      float at[18];
      #pragma unroll
      for (int k = 0; k < 18; ++k) {
        float acc = sF2b[k];
        #pragma unroll
        for (int o = 0; o < 6; ++o) acc += sF2[k * 6 + o] * h[o];
        at[k] = acc;
      }
      #pragma unroll
      for (int c = 0; c < 3; ++c) {
        float m = at[c];
        #pragma unroll
        for (int i = 1; i < 6; ++i) m = fmaxf(m, at[i * 3 + c]);
        float e[6], ssum = 0.0f;
        #pragma unroll
        for (int i = 0; i < 6; ++i) { e[i] = __expf(at[i * 3 + c] - m); ssum += e[i]; }
        float inv = 1.0f / ssum;
        #pragma unroll
        for (int i = 0; i < 6; ++i) {
          float v = al[i * 3 + c] * (e[i] * inv) * sBg[i];
          sBand16[tt][(i * 3 + c) * 6 + n] =
              (unsigned short)(__float_as_uint(v) >> 16);
        }
      }
    }
    __syncthreads();

    // ---- Phase B2: upsample -> packed bf16 enh (ascending f, pair-emit) ----
    if (tid < C_ * TT) {
      const int c  = tid / TT;
      const int tt = tid - c * TT;
      float bnd[36];
      #pragma unroll
      for (int i = 0; i < 6; ++i)
        #pragma unroll
        for (int n = 0; n < 6; ++n)
          bnd[i * 6 + n] =
              __uint_as_float((unsigned)sBand16[tt][(i * 3 + c) * 6 + n] << 16);
      unsigned* rowU = &sPoolU[c * EPL + tt * ERS];
      float pend = 0.0f;                     // f=0 value is 0 (even -> pending)
      float carry = 0.0f;
      #pragma unroll
      for (int i = 0; i < NB_; ++i) {
        #pragma unroll
        for (int j = 0; j < BNB[i]; ++j) {
          const int f = BS[i] + j;
          float src = ((float)j + 0.5f) * 6.0f / (float)BNB[i] - 0.5f;
          src = src > 0.0f ? src : 0.0f;
          int   x0 = (int)src;
          int   x1 = (x0 < 5) ? x0 + 1 : 5;
          float wl = src - (float)x0;
          float v  = bnd[i * 6 + x0] * (1.0f - wl) + bnd[i * 6 + x1] * wl;
          if (j == 0) v += carry;
          if (i < NB_ - 1 && j == BNB[i] - 1) {
            carry = v;                       // overlap bin: deferred to next band
          } else {
            if (f & 1) rowU[f >> 1] = bf16_rne_(pend) | (bf16_rne_(v) << 16);
            else       pend = v;
          }
        }
      }
      rowU[38] = bf16_rne_(pend);            // f=76 (lo), f=77 zero (hi)
      #pragma unroll
      for (int w = 39; w < ERS; ++w) rowU[w] = 0u;
    }
    __syncthreads();

    // ---- Final: flat float4 gate + folded proj + gelu (enh from packed LDS) ----
    float gw[9], pw[9], gb3[3], pb3[3];
    #pragma unroll
    for (int k = 0; k < 9; ++k) { gw[k] = sGw[k]; pw[k] = sPw[k]; }
    #pragma unroll
    for (int k = 0; k < 3; ++k) { gb3[k] = sGb[k]; pb3[k] = sPb[k]; }

    const float* sp0 = specB + (size_t)t0 * F_;
    float* outB = outBase + (size_t)t0 * F_;
    for (int e4 = tid; e4 < (TT * F_) / 4; e4 += 256) {
      const int e = e4 * 4;
      const float4 sA = *(const float4*)(sp0 + e);
      const float4 sB = *(const float4*)(sp0 + PLANE + e);
      const float4 sC = *(const float4*)(sp0 + 2 * PLANE + e);
      float4 oA, oB, oC;
      const float* sAp = (const float*)&sA; const float* sBp = (const float*)&sB;
      const float* sCp = (const float*)&sC;
      float* oAp = (float*)&oA; float* oBp = (float*)&oB; float* oCp = (float*)&oC;
      #pragma unroll
      for (int j = 0; j < 4; ++j) {
        const int idx = e + j;
        const int tt  = idx / F_;            // const-div -> magic mul
        const int f   = idx - tt * F_;
        const int wd  = tt * ERS + (f >> 1);
        const unsigned ua = sPoolU[0 * EPL + wd];
        const unsigned ub = sPoolU[1 * EPL + wd];
        const unsigned uc = sPoolU[2 * EPL + wd];
        const bool hi = (f & 1);
        float e0 = hi ? bh_(ua) : bl_(ua);
        float e1 = hi ? bh_(ub) : bl_(ub);
        float e2 = hi ? bh_(uc) : bl_(uc);
        float sv0 = sAp[j], sv1 = sBp[j], sv2 = sCp[j];
        float r0 = e0 - sv0, r1 = e1 - sv1, r2 = e2 - sv2;
        float e20 = sv0 + sigmoid_(gw[0] * r0 + gw[1] * r1 + gw[2] * r2 + gb3[0]) * r0;
        float e21 = sv1 + sigmoid_(gw[3] * r0 + gw[4] * r1 + gw[5] * r2 + gb3[1]) * r1;
        float e22 = sv2 + sigmoid_(gw[6] * r0 + gw[7] * r1 + gw[8] * r2 + gb3[2]) * r2;
        float y0 = pw[0] * e20 + pw[1] * e21 + pw[2] * e22 + pb3[0];
        float y1 = pw[3] * e20 + pw[4] * e21 + pw[5] * e22 + pb3[1];
        float y2 = pw[6] * e20 + pw[7] * e21 + pw[8] * e22 + pb3[2];
        oAp[j] = gelu_(y0); oBp[j] = gelu_(y1); oCp[j] = gelu_(y2);
      }
      *(float4*)(outB + e) = oA;
      *(float4*)(outB + PLANE + e) = oB;
      *(float4*)(outB + 2 * PLANE + e) = oC;
    }
    __syncthreads();   // protect sPoolU (enh) before next tile's staging
  }
}

} // namespace

extern "C" void kernel_launch(void* const* d_in, const int* in_sizes, int n_in,
                              void* d_out, int out_size, void* d_ws, size_t ws_size,
                              hipStream_t stream) {
  (void)n_in; (void)out_size; (void)ws_size;
  const int B = in_sizes[0] / (C_ * T_ * F_);   // 64
  float* ws = (float*)d_ws;                     // 792 u32 + 12 f32
  prep_kernel<<<1, 128, 0, stream>>>(
      (const float*)d_in[1],  (const float*)d_in[2],  (const float*)d_in[3],
      (const float*)d_in[13], (const float*)d_in[14], (const float*)d_in[15],
      (const float*)d_in[16], (const float*)d_in[17], (const float*)d_in[18], ws);
  dim3 grid(T_ / (TT * NT), B);                 // (50, 64)
  sleepband_kernel<<<grid, 256, 0, stream>>>(
      (const float*)d_in[0],  ws,
      (const float*)d_in[4],  (const float*)d_in[5],
      (const float*)d_in[6],  (const float*)d_in[7],  (const float*)d_in[8],
      (const float*)d_in[9],  (const float*)d_in[10], (const float*)d_in[11],
      (const float*)d_in[12], (float*)d_out);
}

// Round 15
// 241.096 us; speedup vs baseline: 1.0298x; 1.0298x over previous
//
#include <hip/hip_runtime.h>
#include <math.h>

namespace {

constexpr int C_ = 3, T_ = 3000, F_ = 103, NB_ = 6;
constexpr int TT = 20;                       // t-steps per tile
constexpr int NT = 3;                        // tiles per block; 3000/(20*3)=50 chunks
constexpr int BS[NB_]  = {1, 10, 20, 30, 40, 61};
constexpr int BNB[NB_] = {10, 11, 11, 11, 22, 16};
// packed-on-global-parity weight/spec word geometry
constexpr int WSTART[NB_] = {0, 5, 10, 15, 20, 30};  // BS[i]>>1
constexpr int WCNT[NB_]   = {6, 6, 6, 6, 11, 9};     // words covering each band
constexpr int WOFF[NB_]   = {0, 6, 12, 18, 24, 35};  // cumsum WCNT; row = 44
constexpr int WROW = 44;
constexpr int WTOTU = 18 * WROW;             // 792 packed u32 weights
constexpr int SPW = 39;                      // packed spec words per (c,tt) row (f 0..77)
constexpr int SPECW = C_ * TT * SPW;         // 2340
constexpr int ERS = 52;                      // enh row stride (u32), f 0..103
constexpr int EPL = TT * ERS;                // 1040 per c plane
constexpr int POOLU = 3 * EPL;               // 3120 u32 >= SPECW (aliased)
constexpr int PLANE = T_ * F_;               // 309000

__device__ __forceinline__ float softplus_(float x) {
  return fmaxf(x, 0.0f) + log1pf(expf(-fabsf(x)));
}
__device__ __forceinline__ float sigmoid_(float z) {
  return 1.0f / (1.0f + __expf(-z));
}
__device__ __forceinline__ float gelu_(float x) {
  return x * sigmoid_(1.595769122f * x * (1.0f + 0.044715f * x * x));
}
__device__ __forceinline__ unsigned bf16_rne_(float x) {
  unsigned b = __float_as_uint(x);
  b += 0x7FFFu + ((b >> 16) & 1u);
  return b >> 16;
}
__device__ __forceinline__ float bl_(unsigned u) { return __uint_as_float(u << 16); }
__device__ __forceinline__ float bh_(unsigned u) { return __uint_as_float(u & 0xffff0000u); }
// interp tap for band-local bin j of a band with nb bins; folds to literals on unroll
__device__ __forceinline__ float itp_(const float* bn, int j, int nb) {
  float src = ((float)j + 0.5f) * 6.0f / (float)nb - 0.5f;
  src = src > 0.0f ? src : 0.0f;
  int x0 = (int)src;
  int x1 = (x0 < 5) ? x0 + 1 : 5;
  float wl = src - (float)x0;
  return bn[x0] * (1.0f - wl) + bn[x1] * wl;
}

// ---- pre-kernel: global-parity packed bf16 gaussian bank + folded proj/BN -----
__global__ __launch_bounds__(128)
void prep_kernel(const float* __restrict__ centers,
                 const float* __restrict__ widths,
                 const float* __restrict__ gains,
                 const float* __restrict__ proj_w,
                 const float* __restrict__ proj_b,
                 const float* __restrict__ bn_gamma,
                 const float* __restrict__ bn_beta,
                 const float* __restrict__ bn_mean,
                 const float* __restrict__ bn_var,
                 float* __restrict__ ws)
{
  unsigned* wsU = (unsigned*)ws;
  const int q = threadIdx.x;
  if (q < 108) {
    int i = q / 18;
    int p = q - i * 18;                       // c*6+n
    int s = BS[i], nb = BNB[i];
    float mu = softplus_(centers[q]) + (float)s;
    mu = fminf(fmaxf(mu, (float)s), (float)(s + nb - 1));
    float sd = softplus_(widths[q]) + 0.001f;
    sd = fminf(fmaxf(sd, 0.5f), 2.0f * (float)nb / 6.0f);
    float sum = 0.0f;
    for (int f = 0; f < nb; ++f) {
      float d = ((float)f - mu) / sd;
      sum += __expf(-0.5f * d * d);
    }
    float sc = gains[q] / (sum + 1e-6f);
    float wtmp[22];
    for (int f = 0; f < nb; ++f) {
      float d = ((float)f - mu) / sd;
      wtmp[f] = sc * __expf(-0.5f * d * d);
    }
    for (int e = 0; e < WCNT[i]; ++e) {
      int flo = 2 * (WSTART[i] + e) - s;      // band-local index of lo slot
      int fhi = flo + 1;
      unsigned lo = (flo >= 0 && flo < nb) ? bf16_rne_(wtmp[flo]) : 0u;
      unsigned hi = (fhi >= 0 && fhi < nb) ? bf16_rne_(wtmp[fhi]) : 0u;
      wsU[p * WROW + WOFF[i] + e] = lo | (hi << 16);
    }
  } else if (q < 117) {
    int k = q - 108, d = k / 3;
    float sc = bn_gamma[d] / sqrtf(bn_var[d] + 1e-5f);
    ws[WTOTU + k] = proj_w[k] * sc;
  } else if (q < 120) {
    int d = q - 117;
    float sc = bn_gamma[d] / sqrtf(bn_var[d] + 1e-5f);
    ws[WTOTU + 9 + d] = (proj_b[d] - bn_mean[d]) * sc + bn_beta[d];
  }
}

// ---- main kernel: R13 structure + wave-parallel B2 ----------------------------
__global__ __launch_bounds__(256, 6)
void sleepband_kernel(const float* __restrict__ spec,
                      const float* __restrict__ ws,
                      const float* __restrict__ align_w,
                      const float* __restrict__ align_b,
                      const float* __restrict__ fc1_w,
                      const float* __restrict__ fc1_b,
                      const float* __restrict__ fc2_w,
                      const float* __restrict__ fc2_b,
                      const float* __restrict__ band_gain,
                      const float* __restrict__ gate_w,
                      const float* __restrict__ gate_b,
                      float* __restrict__ out)
{
  // pool (u32): [stage/A] packed spec [c][tt][39]  ||  [B2/final] packed enh [c][tt][52]
  __shared__ unsigned sPoolU[POOLU];
  __shared__ unsigned sWu[WTOTU];        // packed bf16 weight pairs, persistent
  __shared__ float sBand[TT][109];       // odd stride -> conflict-free
  __shared__ float sAw[54], sAb[18], sF1[108], sF1b[6], sF2[108], sF2b[18],
                   sBg[6], sGw[9], sGb[3], sPw[9], sPb[3];

  const int tid = threadIdx.x;
  const int b   = blockIdx.y;
  const float* specB = spec + (size_t)b * C_ * PLANE;
  float* outBase = out + (size_t)b * C_ * PLANE;
  const unsigned* wsU = (const unsigned*)ws;

  // ---- one-time prologue: params + packed gaussian weights ----
  for (int k = tid; k < WTOTU; k += 256) sWu[k] = wsU[k];
  if (tid < 54)  sAw[tid]  = align_w[tid];
  if (tid < 18)  sAb[tid]  = align_b[tid];
  if (tid < 108) sF1[tid]  = fc1_w[tid];
  if (tid < 6)   sF1b[tid] = fc1_b[tid];
  if (tid < 108) sF2[tid]  = fc2_w[tid];
  if (tid < 18)  sF2b[tid] = fc2_b[tid];
  if (tid < 6)   sBg[tid]  = band_gain[tid];
  if (tid < 9)   sGw[tid]  = gate_w[tid];
  if (tid < 3)   sGb[tid]  = gate_b[tid];
  if (tid < 9)   sPw[tid]  = ws[WTOTU + tid];
  if (tid < 3)   sPb[tid]  = ws[WTOTU + 9 + tid];

  for (int tile = 0; tile < NT; ++tile) {
    const int t0 = (blockIdx.x * NT + tile) * TT;

    // ---- stage spec as packed bf16 pairs (f 0..77) ----
    for (int li = tid; li < SPECW; li += 256) {
      int c   = li / (TT * SPW);
      int rem = li - c * (TT * SPW);
      int tt  = rem / SPW;
      int w   = rem - tt * SPW;
      const float* gr = specB + (size_t)c * PLANE + (size_t)(t0 + tt) * F_;
      unsigned lo = bf16_rne_(gr[2 * w]);
      unsigned hi = bf16_rne_(gr[2 * w + 1]);
      sPoolU[li] = lo | (hi << 16);
    }
    __syncthreads();

    // ---- Phase A: filt via packed spec x packed weights, n-pair tasks (180) ----
    if (tid < 180) {
      const int g  = tid / TT;             // c*3 + np
      const int tt = tid - g * TT;
      const int c  = g / 3;
      const int np = g - c * 3;
      const int n0 = 2 * np;
      const unsigned* srow = &sPoolU[(c * TT + tt) * SPW];
      const unsigned* w0 = &sWu[(c * 6 + n0) * WROW];
      const unsigned* w1 = w0 + WROW;
      #pragma unroll
      for (int i = 0; i < NB_; ++i) {
        float a0 = 0.0f, a1 = 0.0f;
        #pragma unroll
        for (int e = 0; e < WCNT[i]; ++e) {
          unsigned su = srow[WSTART[i] + e];
          float s0 = bl_(su), s1 = bh_(su);
          unsigned u0 = w0[WOFF[i] + e], u1 = w1[WOFF[i] + e];
          a0 += s0 * bl_(u0); a0 += s1 * bh_(u0);
          a1 += s0 * bl_(u1); a1 += s1 * bh_(u1);
        }
        sBand[tt][(i * 3 + c) * 6 + n0]     = a0;
        sBand[tt][(i * 3 + c) * 6 + n0 + 1] = a1;
      }
    }
    __syncthreads();

    // ---- Phase B: align + MLP + softmax + scale (120 tasks) ----
    if (tid < 6 * TT) {
      int n  = tid / TT;
      int tt = tid - n * TT;
      float al[18];
      #pragma unroll
      for (int i = 0; i < 6; ++i) {
        float f0 = sBand[tt][(i * 3 + 0) * 6 + n];
        float f1 = sBand[tt][(i * 3 + 1) * 6 + n];
        float f2 = sBand[tt][(i * 3 + 2) * 6 + n];
        #pragma unroll
        for (int d = 0; d < 3; ++d)
          al[i * 3 + d] = sAw[i * 9 + d * 3 + 0] * f0 + sAw[i * 9 + d * 3 + 1] * f1 +
                          sAw[i * 9 + d * 3 + 2] * f2 + sAb[i * 3 + d];
      }
      float h[6];
      #pragma unroll
      for (int o = 0; o < 6; ++o) {
        float acc = sF1b[o];
        #pragma unroll
        for (int k = 0; k < 18; ++k) acc += sF1[o * 18 + k] * al[k];
        h[o] = gelu_(acc);
      }
      float at[18];
      #pragma unroll
      for (int k = 0; k < 18; ++k) {
        float acc = sF2b[k];
        #pragma unroll
        for (int o = 0; o < 6; ++o) acc += sF2[k * 6 + o] * h[o];
        at[k] = acc;
      }
      #pragma unroll
      for (int c = 0; c < 3; ++c) {
        float m = at[c];
        #pragma unroll
        for (int i = 1; i < 6; ++i) m = fmaxf(m, at[i * 3 + c]);
        float e[6], ssum = 0.0f;
        #pragma unroll
        for (int i = 0; i < 6; ++i) { e[i] = __expf(at[i * 3 + c] - m); ssum += e[i]; }
        float inv = 1.0f / ssum;
        #pragma unroll
        for (int i = 0; i < 6; ++i)
          sBand[tt][(i * 3 + c) * 6 + n] = al[i * 3 + c] * (e[i] * inv) * sBg[i];
      }
    }
    __syncthreads();

    // ---- Phase B2: wave-parallel upsample -> packed bf16 enh ----
    // q = wave id (uniform branch per wave); lane = (c,tt). 240/256 lanes active.
    {
      const int lane = tid & 63;
      const int q    = tid >> 6;
      if (lane < 60) {
        const int c  = lane / 20;
        const int tt = lane - c * 20;
        const float* bb = &sBand[tt][0];
        unsigned* rowU = &sPoolU[c * EPL + tt * ERS];
        if (q == 0) {
          // f = 0..19 : words 0..9 ; bands 0 (j=0..9) and 1 (j=0..9), f10 = b0[9]+b1[0]
          float b0[6], b1[6];
          #pragma unroll
          for (int n = 0; n < 6; ++n) { b0[n] = bb[(0 + c) * 6 + n]; b1[n] = bb[(3 + c) * 6 + n]; }
          float v[20];
          v[0] = 0.0f;
          #pragma unroll
          for (int j = 0; j < 10; ++j) v[1 + j] = itp_(b0, j, 10);
          v[10] += itp_(b1, 0, 11);
          #pragma unroll
          for (int j = 1; j < 10; ++j) v[10 + j] = itp_(b1, j, 11);
          #pragma unroll
          for (int w = 0; w < 10; ++w)
            rowU[w] = bf16_rne_(v[2 * w]) | (bf16_rne_(v[2 * w + 1]) << 16);
        } else if (q == 1) {
          // f = 20..39 : words 10..19 ; f20=b1[10]+b2[0]; f21..30=b2; f30+=b3[0]; f31..39=b3
          float b1[6], b2[6], b3[6];
          #pragma unroll
          for (int n = 0; n < 6; ++n) {
            b1[n] = bb[(3 + c) * 6 + n]; b2[n] = bb[(6 + c) * 6 + n]; b3[n] = bb[(9 + c) * 6 + n];
          }
          float v[20];
          v[0] = itp_(b1, 10, 11) + itp_(b2, 0, 11);
          #pragma unroll
          for (int j = 1; j < 11; ++j) v[j] = itp_(b2, j, 11);
          v[10] += itp_(b3, 0, 11);
          #pragma unroll
          for (int j = 1; j < 10; ++j) v[10 + j] = itp_(b3, j, 11);
          #pragma unroll
          for (int w = 0; w < 10; ++w)
            rowU[10 + w] = bf16_rne_(v[2 * w]) | (bf16_rne_(v[2 * w + 1]) << 16);
        } else if (q == 2) {
          // f = 40..61 : words 20..30 ; f40=b3[10]+b4[0]; f41..60=b4; f61=b4[21]+b5[0]
          float b3[6], b4[6];
          #pragma unroll
          for (int n = 0; n < 6; ++n) { b3[n] = bb[(9 + c) * 6 + n]; b4[n] = bb[(12 + c) * 6 + n]; }
          const float b5_0 = bb[(15 + c) * 6 + 0];
          float v[22];
          v[0] = itp_(b3, 10, 11) + itp_(b4, 0, 22);
          #pragma unroll
          for (int j = 1; j < 21; ++j) v[j] = itp_(b4, j, 22);
          v[21] = itp_(b4, 21, 22) + b5_0;   // itp_(b5,0,16) == b5[0] (src clamps to 0)
          #pragma unroll
          for (int w = 0; w < 11; ++w)
            rowU[20 + w] = bf16_rne_(v[2 * w]) | (bf16_rne_(v[2 * w + 1]) << 16);
        } else {
          // f = 62..77 : words 31..38 ; band5 j=1..15 ; f77=0 ; zero words 39..51
          float b5[6];
          #pragma unroll
          for (int n = 0; n < 6; ++n) b5[n] = bb[(15 + c) * 6 + n];
          float v[16];
          #pragma unroll
          for (int j = 1; j < 16; ++j) v[j - 1] = itp_(b5, j, 16);
          v[15] = 0.0f;                      // f = 77
          #pragma unroll
          for (int w = 0; w < 8; ++w)
            rowU[31 + w] = bf16_rne_(v[2 * w]) | (bf16_rne_(v[2 * w + 1]) << 16);
          #pragma unroll
          for (int w = 39; w < ERS; ++w) rowU[w] = 0u;
        }
      }
    }
    __syncthreads();

    // ---- Final: flat float4 gate + folded proj + gelu (enh from packed LDS) ----
    float gw[9], pw[9], gb3[3], pb3[3];
    #pragma unroll
    for (int k = 0; k < 9; ++k) { gw[k] = sGw[k]; pw[k] = sPw[k]; }
    #pragma unroll
    for (int k = 0; k < 3; ++k) { gb3[k] = sGb[k]; pb3[k] = sPb[k]; }

    const float* sp0 = specB + (size_t)t0 * F_;
    float* outB = outBase + (size_t)t0 * F_;
    for (int e4 = tid; e4 < (TT * F_) / 4; e4 += 256) {
      const int e = e4 * 4;
      const float4 sA = *(const float4*)(sp0 + e);
      const float4 sB = *(const float4*)(sp0 + PLANE + e);
      const float4 sC = *(const float4*)(sp0 + 2 * PLANE + e);
      float4 oA, oB, oC;
      const float* sAp = (const float*)&sA; const float* sBp = (const float*)&sB;
      const float* sCp = (const float*)&sC;
      float* oAp = (float*)&oA; float* oBp = (float*)&oB; float* oCp = (float*)&oC;
      #pragma unroll
      for (int j = 0; j < 4; ++j) {
        const int idx = e + j;
        const int tt  = idx / F_;            // const-div -> magic mul
        const int f   = idx - tt * F_;
        const int wd  = tt * ERS + (f >> 1);
        const unsigned ua = sPoolU[0 * EPL + wd];
        const unsigned ub = sPoolU[1 * EPL + wd];
        const unsigned uc = sPoolU[2 * EPL + wd];
        const bool hi = (f & 1);
        float e0 = hi ? bh_(ua) : bl_(ua);
        float e1 = hi ? bh_(ub) : bl_(ub);
        float e2 = hi ? bh_(uc) : bl_(uc);
        float sv0 = sAp[j], sv1 = sBp[j], sv2 = sCp[j];
        float r0 = e0 - sv0, r1 = e1 - sv1, r2 = e2 - sv2;
        float e20 = sv0 + sigmoid_(gw[0] * r0 + gw[1] * r1 + gw[2] * r2 + gb3[0]) * r0;
        float e21 = sv1 + sigmoid_(gw[3] * r0 + gw[4] * r1 + gw[5] * r2 + gb3[1]) * r1;
        float e22 = sv2 + sigmoid_(gw[6] * r0 + gw[7] * r1 + gw[8] * r2 + gb3[2]) * r2;
        float y0 = pw[0] * e20 + pw[1] * e21 + pw[2] * e22 + pb3[0];
        float y1 = pw[3] * e20 + pw[4] * e21 + pw[5] * e22 + pb3[1];
        float y2 = pw[6] * e20 + pw[7] * e21 + pw[8] * e22 + pb3[2];
        oAp[j] = gelu_(y0); oBp[j] = gelu_(y1); oCp[j] = gelu_(y2);
      }
      *(float4*)(outB + e) = oA;
      *(float4*)(outB + PLANE + e) = oB;
      *(float4*)(outB + 2 * PLANE + e) = oC;
    }
    __syncthreads();   // protect sPoolU (enh) before next tile's staging
  }
}

} // namespace

extern "C" void kernel_launch(void* const* d_in, const int* in_sizes, int n_in,
                              void* d_out, int out_size, void* d_ws, size_t ws_size,
                              hipStream_t stream) {
  (void)n_in; (void)out_size; (void)ws_size;
  const int B = in_sizes[0] / (C_ * T_ * F_);   // 64
  float* ws = (float*)d_ws;                     // 792 u32 + 12 f32
  prep_kernel<<<1, 128, 0, stream>>>(
      (const float*)d_in[1],  (const float*)d_in[2],  (const float*)d_in[3],
      (const float*)d_in[13], (const float*)d_in[14], (const float*)d_in[15],
      (const float*)d_in[16], (const float*)d_in[17], (const float*)d_in[18], ws);
  dim3 grid(T_ / (TT * NT), B);                 // (50, 64)
  sleepband_kernel<<<grid, 256, 0, stream>>>(
      (const float*)d_in[0],  ws,
      (const float*)d_in[4],  (const float*)d_in[5],
      (const float*)d_in[6],  (const float*)d_in[7],  (const float*)d_in[8],
      (const float*)d_in[9],  (const float*)d_in[10], (const float*)d_in[11],
      (const float*)d_in[12], (float*)d_out);
}